// Round 1
// 994.532 us; speedup vs baseline: 1.2074x; 1.2074x over previous
//
#include <hip/hip_runtime.h>
#include <hip/hip_bf16.h>

typedef __attribute__((ext_vector_type(8))) short short8;
typedef __attribute__((ext_vector_type(4))) float f32x4;

__device__ __forceinline__ unsigned short f2bf(float f) {
    __hip_bfloat16 h = __float2bfloat16(f);
    union { __hip_bfloat16 h; unsigned short u; } c; c.h = h; return c.u;
}

typedef __attribute__((address_space(1))) const unsigned int gas_u32;
typedef __attribute__((address_space(3))) unsigned int las_u32;

// async global->LDS, 16B per lane; lds dst must be the wave-uniform base
__device__ __forceinline__ void gload_lds16(const unsigned short* g, unsigned short* l) {
    __builtin_amdgcn_global_load_lds((gas_u32*)g, (las_u32*)l, 16, 0, 0);
}

// ---------------------------------------------------------------- fp32 -> bf16
__global__ void cvt_bf16_kernel(const float* __restrict__ src,
                                unsigned short* __restrict__ dst, long n8) {
    long stride = (long)gridDim.x * 256;
    for (long t = (long)blockIdx.x * 256 + threadIdx.x; t < n8; t += stride) {
        long i = t * 8;
        float4 f0 = *reinterpret_cast<const float4*>(src + i);
        float4 f1 = *reinterpret_cast<const float4*>(src + i + 4);
        uint4 u;
        u.x = ((unsigned)f2bf(f0.y) << 16) | f2bf(f0.x);
        u.y = ((unsigned)f2bf(f0.w) << 16) | f2bf(f0.z);
        u.z = ((unsigned)f2bf(f1.y) << 16) | f2bf(f1.x);
        u.w = ((unsigned)f2bf(f1.w) << 16) | f2bf(f1.z);
        *reinterpret_cast<uint4*>(dst + i) = u;
    }
}

// ---------------------------------------------------------------- bias expand
// bias_full[h*9604 + n*98 + m] = bias_table[rel_index[n*98+m]*8 + h]
__global__ void bias_expand_kernel(const float* __restrict__ bias_table,
                                   const int* __restrict__ rel_index,
                                   float* __restrict__ bias_full) {
    int idx = blockIdx.x * 256 + threadIdx.x;
    if (idx >= 8 * 9604) return;
    int h = idx / 9604;
    int r = idx - h * 9604;
    bias_full[idx] = bias_table[rel_index[r] * 8 + h];
}

// ---------------------------------------------------------------- vt pad zero
__global__ void vt_zerofill_kernel(unsigned short* __restrict__ vtws) {
    int idx = blockIdx.x * 256 + threadIdx.x;  // 16384*32*7 uint writes
    if (idx >= 16384 * 32 * 7) return;
    int bhd = idx / 7, j = idx - bhd * 7;
    unsigned* p = reinterpret_cast<unsigned*>(vtws + (long)bhd * 112 + 98);
    p[j] = 0;
}

// ---------------------------------------------------------------- QKV GEMM
// m97 structure: 128x128 tile, BK=64, linear bf16 LDS, global_load_lds x16B.
__global__ __launch_bounds__(256, 4)
void gemm_qkv_kernel(const unsigned short* __restrict__ Xb,   // (M,256) bf16
                     const unsigned short* __restrict__ Wb,   // (768,256) bf16
                     const float* __restrict__ bias,
                     unsigned short* __restrict__ qws,
                     unsigned short* __restrict__ kws,
                     unsigned short* __restrict__ vtws) {
    __shared__ unsigned short As[128 * 64];
    __shared__ unsigned short Bs[128 * 64];
    const int tid = threadIdx.x;
    const int wave = tid >> 6, lane = tid & 63;
    const int q4 = lane >> 4, l16 = lane & 15;
    const int wr = wave >> 1, wc = wave & 1;

    // XCD-aware bijective swizzle (nwg = 6*1568 = 9408, 9408 % 8 == 0)
    const int nwg = gridDim.x * gridDim.y;
    const int bid = blockIdx.y * gridDim.x + blockIdx.x;
    const int swz = (bid & 7) * (nwg >> 3) + (bid >> 3);
    const int bx = swz % gridDim.x;
    const int by = swz / gridDim.x;

    const long m0 = (long)by * 128;
    const int n0 = bx * 128;

    const int srow = lane >> 3;         // row within 8-row chunk
    const int scol = (lane & 7) << 3;   // col (elems) within 64

    f32x4 acc[4][4];
#pragma unroll
    for (int i = 0; i < 4; ++i)
#pragma unroll
        for (int j = 0; j < 4; ++j) acc[i][j] = (f32x4){0.f, 0.f, 0.f, 0.f};

    for (int ks = 0; ks < 256; ks += 64) {
#pragma unroll
        for (int i = 0; i < 4; ++i) {
            int c = wave * 4 + i;                       // chunk: 8 rows x 64 cols
            gload_lds16(Xb + (m0 + c * 8 + srow) * 256 + ks + scol, &As[c * 512]);
            gload_lds16(Wb + (long)(n0 + c * 8 + srow) * 256 + ks + scol, &Bs[c * 512]);
        }
        __syncthreads();   // compiler drains vmcnt+lgkmcnt here
#pragma unroll
        for (int s = 0; s < 2; ++s) {
            short8 a[4], b[4];
#pragma unroll
            for (int i = 0; i < 4; ++i)
                a[i] = *reinterpret_cast<const short8*>(&As[(wr * 64 + i * 16 + l16) * 64 + s * 32 + q4 * 8]);
#pragma unroll
            for (int j = 0; j < 4; ++j)
                b[j] = *reinterpret_cast<const short8*>(&Bs[(wc * 64 + j * 16 + l16) * 64 + s * 32 + q4 * 8]);
#pragma unroll
            for (int i = 0; i < 4; ++i)
#pragma unroll
                for (int j = 0; j < 4; ++j)
                    acc[i][j] = __builtin_amdgcn_mfma_f32_16x16x32_bf16(a[i], b[j], acc[i][j], 0, 0, 0);
        }
        __syncthreads();
    }
    // epilogue: scatter per-head; V goes out transposed (bh, d, 112)
#pragma unroll
    for (int i = 0; i < 4; ++i) {
#pragma unroll
        for (int r = 0; r < 4; ++r) {
            long row = m0 + wr * 64 + i * 16 + q4 * 4 + r;
            int b_ = (int)(row / 98);
            int n_ = (int)(row - (long)b_ * 98);
#pragma unroll
            for (int j = 0; j < 4; ++j) {
                int col = n0 + wc * 64 + j * 16 + l16;
                float vv = acc[i][j][r] + bias[col];
                int which = col >> 8;
                int h = (col >> 5) & 7;
                int d = col & 31;
                if (which == 2) {
                    vtws[((long)(b_ * 8 + h) * 32 + d) * 112 + n_] = f2bf(vv);
                } else {
                    unsigned short* dst = which ? kws : qws;
                    dst[((long)(b_ * 8 + h) * 98 + n_) * 32 + d] = f2bf(vv);
                }
            }
        }
    }
}

// ---------------------------------------------------------------- attention
// one block (256 thr) per (b,h). S^T via mfma(A=K,B=Q); P stays in registers,
// transformed to PV A-operand layout with cross-quad shuffles (no P LDS).
__global__ __launch_bounds__(256, 4)
void attn_kernel(const unsigned short* __restrict__ q,
                 const unsigned short* __restrict__ k,
                 const unsigned short* __restrict__ vt,   // (bh,32,112)
                 const float* __restrict__ mask,          // (512,98,98)
                 const float* __restrict__ bias_full,     // (8,98,98)
                 unsigned short* __restrict__ attn_out) {
    __shared__ unsigned short Qs[112 * 40];   // 8960 B
    __shared__ unsigned short Ks[112 * 40];   // 8960 B
    __shared__ unsigned short Vt[32 * 136];   // 8704 B (cols 0..127 used)

    const int tid = threadIdx.x;
    const int wave = tid >> 6, lane = tid & 63;
    const int q4 = lane >> 4, l16 = lane & 15;
    const int bh = blockIdx.x;
    const int b = bh >> 3, h = bh & 7;
    const int w = b & 511;
    const long base = (long)bh * 98 * 32;

    for (int idx = tid; idx < 448; idx += 256) {
        int n = idx >> 2, dg = (idx & 3) * 8;
        uint4 val = make_uint4(0, 0, 0, 0);
        if (n < 98) val = *reinterpret_cast<const uint4*>(q + base + n * 32 + dg);
        *reinterpret_cast<uint4*>(&Qs[n * 40 + dg]) = val;
    }
    for (int idx = tid; idx < 448; idx += 256) {
        int n = idx >> 2, dg = (idx & 3) * 8;
        uint4 val = make_uint4(0, 0, 0, 0);
        if (n < 98) val = *reinterpret_cast<const uint4*>(k + base + n * 32 + dg);
        *reinterpret_cast<uint4*>(&Ks[n * 40 + dg]) = val;
    }
    const unsigned short* vtp = vt + (long)bh * 3584;
    for (int idx = tid; idx < 448; idx += 256) {
        int d = idx / 14, ch = idx - d * 14;
        *reinterpret_cast<uint4*>(&Vt[d * 136 + ch * 8]) =
            *reinterpret_cast<const uint4*>(vtp + d * 112 + ch * 8);
    }
    if (tid < 64) {  // zero Vt cols [112,128)
        int d = tid >> 1, c = tid & 1;
        *reinterpret_cast<uint4*>(&Vt[d * 136 + 112 + c * 8]) = make_uint4(0, 0, 0, 0);
    }
    __syncthreads();

    const float scale = 0.17677669529663687f;  // 1/sqrt(32)
    const float* maskp = mask + (long)w * 9604;
    const float* biasp = bias_full + (long)h * 9604;
    const long obase = (long)b * 98 * 256 + h * 32;

    for (int tr = wave; tr < 7; tr += 4) {
        const int n = tr * 16 + l16;           // this lane's query index
        short8 bq = *reinterpret_cast<const short8*>(&Qs[(tr * 16 + l16) * 40 + q4 * 8]);
        f32x4 pv[7];
#pragma unroll
        for (int i = 0; i < 7; ++i) {
            short8 ak = *reinterpret_cast<const short8*>(&Ks[(i * 16 + l16) * 40 + q4 * 8]);
            f32x4 d = (f32x4){0.f, 0.f, 0.f, 0.f};
            d = __builtin_amdgcn_mfma_f32_16x16x32_bf16(ak, bq, d, 0, 0, 0);
            // d[r] = S[n][m], m = i*16 + q4*4 + r
            int m0 = i * 16 + q4 * 4;
            f32x4 o;
            if (n < 98 && m0 + 3 < 98) {
                float2 mk0 = *reinterpret_cast<const float2*>(maskp + n * 98 + m0);
                float2 mk1 = *reinterpret_cast<const float2*>(maskp + n * 98 + m0 + 2);
                float2 bb0 = *reinterpret_cast<const float2*>(biasp + n * 98 + m0);
                float2 bb1 = *reinterpret_cast<const float2*>(biasp + n * 98 + m0 + 2);
                o[0] = d[0] * scale + mk0.x + bb0.x;
                o[1] = d[1] * scale + mk0.y + bb0.y;
                o[2] = d[2] * scale + mk1.x + bb1.x;
                o[3] = d[3] * scale + mk1.y + bb1.y;
            } else {
#pragma unroll
                for (int r = 0; r < 4; ++r) {
                    int m = m0 + r;
                    o[r] = (n < 98 && m < 98)
                         ? d[r] * scale + maskp[n * 98 + m] + biasp[n * 98 + m]
                         : -1e30f;
                }
            }
            pv[i] = o;
        }
        // softmax over m (in-lane 28 values, then cross-quad lanes l16+{16,32,48})
        float mx = -1e30f;
#pragma unroll
        for (int i = 0; i < 7; ++i)
#pragma unroll
            for (int r = 0; r < 4; ++r) mx = fmaxf(mx, pv[i][r]);
        mx = fmaxf(mx, __shfl_xor(mx, 16));
        mx = fmaxf(mx, __shfl_xor(mx, 32));
        float sm = 0.f;
#pragma unroll
        for (int i = 0; i < 7; ++i)
#pragma unroll
            for (int r = 0; r < 4; ++r) {
                float e = __expf(pv[i][r] - mx);
                pv[i][r] = e;
                sm += e;
            }
        sm += __shfl_xor(sm, 16);
        sm += __shfl_xor(sm, 32);
        float rinv = 1.f / sm;
        // pack normalized P as bf16 pairs
        unsigned up[8][2];
#pragma unroll
        for (int i = 0; i < 7; ++i) {
            up[i][0] = ((unsigned)f2bf(pv[i][1] * rinv) << 16) | f2bf(pv[i][0] * rinv);
            up[i][1] = ((unsigned)f2bf(pv[i][3] * rinv) << 16) | f2bf(pv[i][2] * rinv);
        }
        up[7][0] = 0; up[7][1] = 0;
        // PV: shuffle P into A-operand layout, accumulate over kc
        f32x4 o0 = (f32x4){0.f, 0.f, 0.f, 0.f};
        f32x4 o1 = (f32x4){0.f, 0.f, 0.f, 0.f};
        const int srcA = ((q4 & 1) * 2) * 16 + l16;
        const int srcB = srcA + 16;
        const bool hi = (q4 >= 2);
#pragma unroll
        for (int kc = 0; kc < 4; ++kc) {
            int ie = 2 * kc, io = 2 * kc + 1;
            unsigned a0e = __shfl(up[ie][0], srcA), a0o = __shfl(up[io][0], srcA);
            unsigned a1e = __shfl(up[ie][1], srcA), a1o = __shfl(up[io][1], srcA);
            unsigned b0e = __shfl(up[ie][0], srcB), b0o = __shfl(up[io][0], srcB);
            unsigned b1e = __shfl(up[ie][1], srcB), b1o = __shfl(up[io][1], srcB);
            union { uint4 u; short8 s; } cvt;
            cvt.u.x = hi ? a0o : a0e;
            cvt.u.y = hi ? a1o : a1e;
            cvt.u.z = hi ? b0o : b0e;
            cvt.u.w = hi ? b1o : b1e;
            short8 bv0 = *reinterpret_cast<const short8*>(&Vt[l16 * 136 + kc * 32 + q4 * 8]);
            short8 bv1 = *reinterpret_cast<const short8*>(&Vt[(16 + l16) * 136 + kc * 32 + q4 * 8]);
            o0 = __builtin_amdgcn_mfma_f32_16x16x32_bf16(cvt.s, bv0, o0, 0, 0, 0);
            o1 = __builtin_amdgcn_mfma_f32_16x16x32_bf16(cvt.s, bv1, o1, 0, 0, 0);
        }
        // store: row n' = tr*16 + q4*4 + r, cols d = l16 and 16+l16
#pragma unroll
        for (int r = 0; r < 4; ++r) {
            int nn = tr * 16 + q4 * 4 + r;
            if (nn < 98) {
                attn_out[obase + nn * 256 + l16] = f2bf(o0[r]);
                attn_out[obase + nn * 256 + 16 + l16] = f2bf(o1[r]);
            }
        }
    }
}

// ---------------------------------------------------------------- proj GEMM
__global__ __launch_bounds__(256, 4)
void gemm_proj_kernel(const unsigned short* __restrict__ Abf,  // (M,256) bf16
                      const unsigned short* __restrict__ Wb,   // (256,256) bf16
                      const float* __restrict__ bias,
                      float* __restrict__ out) {
    __shared__ unsigned short As[128 * 64];
    __shared__ unsigned short Bs[128 * 64];
    const int tid = threadIdx.x;
    const int wave = tid >> 6, lane = tid & 63;
    const int q4 = lane >> 4, l16 = lane & 15;
    const int wr = wave >> 1, wc = wave & 1;

    // XCD-aware bijective swizzle (nwg = 2*1568 = 3136, 3136 % 8 == 0)
    const int nwg = gridDim.x * gridDim.y;
    const int bid = blockIdx.y * gridDim.x + blockIdx.x;
    const int swz = (bid & 7) * (nwg >> 3) + (bid >> 3);
    const int bx = swz % gridDim.x;
    const int by = swz / gridDim.x;

    const long m0 = (long)by * 128;
    const int n0 = bx * 128;

    const int srow = lane >> 3;
    const int scol = (lane & 7) << 3;

    f32x4 acc[4][4];
#pragma unroll
    for (int i = 0; i < 4; ++i)
#pragma unroll
        for (int j = 0; j < 4; ++j) acc[i][j] = (f32x4){0.f, 0.f, 0.f, 0.f};

    for (int ks = 0; ks < 256; ks += 64) {
#pragma unroll
        for (int i = 0; i < 4; ++i) {
            int c = wave * 4 + i;
            gload_lds16(Abf + (m0 + c * 8 + srow) * 256 + ks + scol, &As[c * 512]);
            gload_lds16(Wb + (long)(n0 + c * 8 + srow) * 256 + ks + scol, &Bs[c * 512]);
        }
        __syncthreads();
#pragma unroll
        for (int s = 0; s < 2; ++s) {
            short8 a[4], b[4];
#pragma unroll
            for (int i = 0; i < 4; ++i)
                a[i] = *reinterpret_cast<const short8*>(&As[(wr * 64 + i * 16 + l16) * 64 + s * 32 + q4 * 8]);
#pragma unroll
            for (int j = 0; j < 4; ++j)
                b[j] = *reinterpret_cast<const short8*>(&Bs[(wc * 64 + j * 16 + l16) * 64 + s * 32 + q4 * 8]);
#pragma unroll
            for (int i = 0; i < 4; ++i)
#pragma unroll
                for (int j = 0; j < 4; ++j)
                    acc[i][j] = __builtin_amdgcn_mfma_f32_16x16x32_bf16(a[i], b[j], acc[i][j], 0, 0, 0);
        }
        __syncthreads();
    }
#pragma unroll
    for (int i = 0; i < 4; ++i) {
#pragma unroll
        for (int r = 0; r < 4; ++r) {
            long row = m0 + wr * 64 + i * 16 + q4 * 4 + r;
#pragma unroll
            for (int j = 0; j < 4; ++j) {
                int col = n0 + wc * 64 + j * 16 + l16;
                out[row * 256 + col] = acc[i][j][r] + bias[col];
            }
        }
    }
}

// ---------------------------------------------------------------- launch
extern "C" void kernel_launch(void* const* d_in, const int* in_sizes, int n_in,
                              void* d_out, int out_size, void* d_ws, size_t ws_size,
                              hipStream_t stream) {
    (void)in_sizes; (void)n_in; (void)out_size; (void)ws_size;
    const float* x          = (const float*)d_in[0];
    const float* mask       = (const float*)d_in[1];
    const float* qkv_w      = (const float*)d_in[2];
    const float* qkv_b      = (const float*)d_in[3];
    const float* proj_w     = (const float*)d_in[4];
    const float* proj_b     = (const float*)d_in[5];
    const float* bias_table = (const float*)d_in[6];
    const int*   rel_index  = (const int*)d_in[7];
    float* out = (float*)d_out;

    const long QN = 51380224;   // 2048*8*98*32 (bf16 elems)
    const long VT = 58720256;   // 2048*8*32*112 (bf16 elems)
    unsigned short* qws  = (unsigned short*)d_ws;
    unsigned short* kws  = qws + QN;
    unsigned short* vtws = kws + QN;
    unsigned short* aow  = vtws + VT;           // attn_out (M,256) bf16
    float* bias_full = (float*)(aow + QN);      // 8*9604 fp32
    unsigned short* wqkvb  = (unsigned short*)(bias_full + 8 * 9604);  // 768*256 bf16
    unsigned short* wprojb = wqkvb + 768 * 256;                        // 256*256 bf16
    // Xb aliases aow: gemm_qkv's reads of Xb complete (stream order)
    // before attn_kernel writes attn_out into the same buffer.
    unsigned short* xb = aow;

    vt_zerofill_kernel<<<dim3((16384 * 32 * 7 + 255) / 256), dim3(256), 0, stream>>>(vtws);
    bias_expand_kernel<<<dim3((8 * 9604 + 255) / 256), dim3(256), 0, stream>>>(
        bias_table, rel_index, bias_full);
    cvt_bf16_kernel<<<dim3(2048), dim3(256), 0, stream>>>(x, xb, 51380224L / 8);
    cvt_bf16_kernel<<<dim3(96), dim3(256), 0, stream>>>(qkv_w, wqkvb, 196608L / 8);
    cvt_bf16_kernel<<<dim3(32), dim3(256), 0, stream>>>(proj_w, wprojb, 65536L / 8);
    gemm_qkv_kernel<<<dim3(6, 1568), dim3(256), 0, stream>>>(
        xb, wqkvb, qkv_b, qws, kws, vtws);
    attn_kernel<<<dim3(16384), dim3(256), 0, stream>>>(
        qws, kws, vtws, mask, bias_full, aow);
    gemm_proj_kernel<<<dim3(2, 1568), dim3(256), 0, stream>>>(
        aow, wprojb, proj_b, out);
}

// Round 2
// 922.121 us; speedup vs baseline: 1.3022x; 1.0785x over previous
//
#include <hip/hip_runtime.h>
#include <hip/hip_bf16.h>

typedef __attribute__((ext_vector_type(8))) short short8;
typedef __attribute__((ext_vector_type(4))) float f32x4;

__device__ __forceinline__ unsigned short f2bf(float f) {
    __hip_bfloat16 h = __float2bfloat16(f);
    union { __hip_bfloat16 h; unsigned short u; } c; c.h = h; return c.u;
}

typedef __attribute__((address_space(1))) const unsigned int gas_u32;
typedef __attribute__((address_space(3))) unsigned int las_u32;

// async global->LDS, 16B per lane; lds dst must be the wave-uniform base
__device__ __forceinline__ void gload_lds16(const unsigned short* g, unsigned short* l) {
    __builtin_amdgcn_global_load_lds((gas_u32*)g, (las_u32*)l, 16, 0, 0);
}

// ---------------------------------------------------------------- fp32 -> bf16
__global__ void cvt_bf16_kernel(const float* __restrict__ src,
                                unsigned short* __restrict__ dst, long n8) {
    long stride = (long)gridDim.x * 256;
    for (long t = (long)blockIdx.x * 256 + threadIdx.x; t < n8; t += stride) {
        long i = t * 8;
        float4 f0 = *reinterpret_cast<const float4*>(src + i);
        float4 f1 = *reinterpret_cast<const float4*>(src + i + 4);
        uint4 u;
        u.x = ((unsigned)f2bf(f0.y) << 16) | f2bf(f0.x);
        u.y = ((unsigned)f2bf(f0.w) << 16) | f2bf(f0.z);
        u.z = ((unsigned)f2bf(f1.y) << 16) | f2bf(f1.x);
        u.w = ((unsigned)f2bf(f1.w) << 16) | f2bf(f1.z);
        *reinterpret_cast<uint4*>(dst + i) = u;
    }
}

// ---------------------------------------------------------------- mask pad
// mask_pad (512,112,112): cols>=98 -> -1e30 (softmax kill), pad rows -> 0
__global__ void mask_pad_kernel(const float* __restrict__ mask,
                                float* __restrict__ mask_pad) {
    int idx = blockIdx.x * 256 + threadIdx.x;
    if (idx >= 512 * 12544) return;
    int w = idx / 12544, rem = idx - w * 12544;
    int n = rem / 112, m = rem - n * 112;
    float v;
    if (m >= 98) v = -1e30f;
    else if (n >= 98) v = 0.f;
    else v = mask[w * 9604 + n * 98 + m];
    mask_pad[idx] = v;
}

// ---------------------------------------------------------------- bias pad
// bias_pad (8,112,112): gathered rel-pos bias, pads -> 0
__global__ void bias_pad_kernel(const float* __restrict__ bias_table,
                                const int* __restrict__ rel_index,
                                float* __restrict__ bias_pad) {
    int idx = blockIdx.x * 256 + threadIdx.x;
    if (idx >= 8 * 12544) return;
    int h = idx / 12544, rem = idx - h * 12544;
    int n = rem / 112, m = rem - n * 112;
    float v = (n < 98 && m < 98) ? bias_table[rel_index[n * 98 + m] * 8 + h] : 0.f;
    bias_pad[idx] = v;
}

// ---------------------------------------------------------------- vt pad zero
__global__ void vt_zerofill_kernel(unsigned short* __restrict__ vtws) {
    int idx = blockIdx.x * 256 + threadIdx.x;  // 16384*32*7 uint writes
    if (idx >= 16384 * 32 * 7) return;
    int bhd = idx / 7, j = idx - bhd * 7;
    unsigned* p = reinterpret_cast<unsigned*>(vtws + (long)bhd * 112 + 98);
    p[j] = 0;
}

// ---------------------------------------------------------------- QKV GEMM
// m97 structure: 128x128 tile, BK=64, linear bf16 LDS, global_load_lds x16B.
__global__ __launch_bounds__(256, 4)
void gemm_qkv_kernel(const unsigned short* __restrict__ Xb,   // (M,256) bf16
                     const unsigned short* __restrict__ Wb,   // (768,256) bf16
                     const float* __restrict__ bias,
                     unsigned short* __restrict__ qws,
                     unsigned short* __restrict__ kws,
                     unsigned short* __restrict__ vtws) {
    __shared__ unsigned short As[128 * 64];
    __shared__ unsigned short Bs[128 * 64];
    const int tid = threadIdx.x;
    const int wave = tid >> 6, lane = tid & 63;
    const int q4 = lane >> 4, l16 = lane & 15;
    const int wr = wave >> 1, wc = wave & 1;

    // XCD-aware bijective swizzle (nwg = 6*1568 = 9408, 9408 % 8 == 0)
    const int nwg = gridDim.x * gridDim.y;
    const int bid = blockIdx.y * gridDim.x + blockIdx.x;
    const int swz = (bid & 7) * (nwg >> 3) + (bid >> 3);
    const int bx = swz % gridDim.x;
    const int by = swz / gridDim.x;

    const long m0 = (long)by * 128;
    const int n0 = bx * 128;

    const int srow = lane >> 3;         // row within 8-row chunk
    const int scol = (lane & 7) << 3;   // col (elems) within 64

    f32x4 acc[4][4];
#pragma unroll
    for (int i = 0; i < 4; ++i)
#pragma unroll
        for (int j = 0; j < 4; ++j) acc[i][j] = (f32x4){0.f, 0.f, 0.f, 0.f};

    for (int ks = 0; ks < 256; ks += 64) {
#pragma unroll
        for (int i = 0; i < 4; ++i) {
            int c = wave * 4 + i;                       // chunk: 8 rows x 64 cols
            gload_lds16(Xb + (m0 + c * 8 + srow) * 256 + ks + scol, &As[c * 512]);
            gload_lds16(Wb + (long)(n0 + c * 8 + srow) * 256 + ks + scol, &Bs[c * 512]);
        }
        __syncthreads();   // compiler drains vmcnt+lgkmcnt here
#pragma unroll
        for (int s = 0; s < 2; ++s) {
            short8 a[4], b[4];
#pragma unroll
            for (int i = 0; i < 4; ++i)
                a[i] = *reinterpret_cast<const short8*>(&As[(wr * 64 + i * 16 + l16) * 64 + s * 32 + q4 * 8]);
#pragma unroll
            for (int j = 0; j < 4; ++j)
                b[j] = *reinterpret_cast<const short8*>(&Bs[(wc * 64 + j * 16 + l16) * 64 + s * 32 + q4 * 8]);
#pragma unroll
            for (int i = 0; i < 4; ++i)
#pragma unroll
                for (int j = 0; j < 4; ++j)
                    acc[i][j] = __builtin_amdgcn_mfma_f32_16x16x32_bf16(a[i], b[j], acc[i][j], 0, 0, 0);
        }
        __syncthreads();
    }
    // epilogue: scatter per-head; q pre-scaled by 1/sqrt(32); V transposed (bh,d,112)
    const float scale = 0.17677669529663687f;
#pragma unroll
    for (int i = 0; i < 4; ++i) {
#pragma unroll
        for (int r = 0; r < 4; ++r) {
            long row = m0 + wr * 64 + i * 16 + q4 * 4 + r;
            int b_ = (int)(row / 98);
            int n_ = (int)(row - (long)b_ * 98);
#pragma unroll
            for (int j = 0; j < 4; ++j) {
                int col = n0 + wc * 64 + j * 16 + l16;
                float vv = acc[i][j][r] + bias[col];
                int which = col >> 8;
                int h = (col >> 5) & 7;
                int d = col & 31;
                if (which == 2) {
                    vtws[((long)(b_ * 8 + h) * 32 + d) * 112 + n_] = f2bf(vv);
                } else if (which == 1) {
                    kws[((long)(b_ * 8 + h) * 98 + n_) * 32 + d] = f2bf(vv);
                } else {
                    qws[((long)(b_ * 8 + h) * 98 + n_) * 32 + d] = f2bf(vv * scale);
                }
            }
        }
    }
}

// ---------------------------------------------------------------- attention
// one block (448 thr = 7 waves) per (b,h); one 16-row S^T tile per wave.
// XCD swizzle keeps all 32 blocks sharing a mask window on one XCD's L2.
__global__ __launch_bounds__(448, 7)
void attn_kernel(const unsigned short* __restrict__ q,
                 const unsigned short* __restrict__ k,
                 const unsigned short* __restrict__ vt,      // (bh,32,112)
                 const float* __restrict__ mask_pad,         // (512,112,112)
                 const float* __restrict__ bias_pad,         // (8,112,112)
                 unsigned short* __restrict__ attn_out) {
    __shared__ unsigned short Qs[112 * 40];   // 8960 B
    __shared__ unsigned short Ks[112 * 40];   // 8960 B
    __shared__ unsigned short Vt[32 * 136];   // 8704 B (cols 0..127 used)

    const int tid = threadIdx.x;
    const int wave = tid >> 6, lane = tid & 63;
    const int q4 = lane >> 4, l16 = lane & 15;

    // blockIdx -> (b,h) with window locality per XCD (dispatch round-robins d&7)
    const int d0 = blockIdx.x;
    const int xcd = d0 & 7, jj = d0 >> 3;
    const int w = xcd * 64 + (jj >> 5);       // 64 windows per XCD
    const int sub = jj & 31;                  // 4 b-reps x 8 heads share window w
    const int b = (sub >> 3) * 512 + w;
    const int h = sub & 7;
    const int bh = b * 8 + h;
    const long base = (long)bh * 98 * 32;

    {   // stage Q,K: one 16B chunk per thread (448 = 112 rows x 4 chunks)
        int n = tid >> 2, dg = (tid & 3) * 8;
        uint4 vq = make_uint4(0, 0, 0, 0), vk = make_uint4(0, 0, 0, 0);
        if (n < 98) {
            vq = *reinterpret_cast<const uint4*>(q + base + n * 32 + dg);
            vk = *reinterpret_cast<const uint4*>(k + base + n * 32 + dg);
        }
        *reinterpret_cast<uint4*>(&Qs[n * 40 + dg]) = vq;
        *reinterpret_cast<uint4*>(&Ks[n * 40 + dg]) = vk;
    }
    {   // stage Vt: 448 = 32 d-rows x 14 chunks
        const unsigned short* vtp = vt + (long)bh * 3584;
        int d = tid / 14, ch = tid - d * 14;
        *reinterpret_cast<uint4*>(&Vt[d * 136 + ch * 8]) =
            *reinterpret_cast<const uint4*>(vtp + d * 112 + ch * 8);
    }
    if (tid < 64) {  // zero Vt cols [112,128)
        int d = tid >> 1, c = tid & 1;
        *reinterpret_cast<uint4*>(&Vt[d * 136 + 112 + c * 8]) = make_uint4(0, 0, 0, 0);
    }
    __syncthreads();

    const float* mp = mask_pad + (long)w * 12544;
    const float* bp = bias_pad + (long)h * 12544;
    const long obase = (long)b * 98 * 256 + h * 32;

    const int tr = wave;                   // one tile per wave, 7 waves
    const int n = tr * 16 + l16;           // this lane's query row (<112)
    const float* mrow = mp + n * 112;
    const float* brow = bp + n * 112;
    short8 bq = *reinterpret_cast<const short8*>(&Qs[n * 40 + q4 * 8]);
    f32x4 pv[7];
#pragma unroll
    for (int i = 0; i < 7; ++i) {
        short8 ak = *reinterpret_cast<const short8*>(&Ks[(i * 16 + l16) * 40 + q4 * 8]);
        f32x4 d = (f32x4){0.f, 0.f, 0.f, 0.f};
        d = __builtin_amdgcn_mfma_f32_16x16x32_bf16(ak, bq, d, 0, 0, 0);
        // d[r] = S[n][m], m = i*16 + q4*4 + r; q pre-scaled
        int m0 = i * 16 + q4 * 4;
        float4 mk = *reinterpret_cast<const float4*>(mrow + m0);
        float4 bb = *reinterpret_cast<const float4*>(brow + m0);
        pv[i][0] = d[0] + mk.x + bb.x;
        pv[i][1] = d[1] + mk.y + bb.y;
        pv[i][2] = d[2] + mk.z + bb.z;
        pv[i][3] = d[3] + mk.w + bb.w;
    }
    // softmax over m (in-lane 28 values, then cross-quad lanes l16+{16,32,48})
    float mx = -1e30f;
#pragma unroll
    for (int i = 0; i < 7; ++i)
#pragma unroll
        for (int r = 0; r < 4; ++r) mx = fmaxf(mx, pv[i][r]);
    mx = fmaxf(mx, __shfl_xor(mx, 16));
    mx = fmaxf(mx, __shfl_xor(mx, 32));
    float sm = 0.f;
#pragma unroll
    for (int i = 0; i < 7; ++i)
#pragma unroll
        for (int r = 0; r < 4; ++r) {
            float e = __expf(pv[i][r] - mx);
            pv[i][r] = e;
            sm += e;
        }
    sm += __shfl_xor(sm, 16);
    sm += __shfl_xor(sm, 32);
    float rinv = 1.f / sm;
    // pack normalized P as bf16 pairs
    unsigned up[8][2];
#pragma unroll
    for (int i = 0; i < 7; ++i) {
        up[i][0] = ((unsigned)f2bf(pv[i][1] * rinv) << 16) | f2bf(pv[i][0] * rinv);
        up[i][1] = ((unsigned)f2bf(pv[i][3] * rinv) << 16) | f2bf(pv[i][2] * rinv);
    }
    up[7][0] = 0; up[7][1] = 0;
    // PV: shuffle P into A-operand layout, accumulate over kc
    f32x4 o0 = (f32x4){0.f, 0.f, 0.f, 0.f};
    f32x4 o1 = (f32x4){0.f, 0.f, 0.f, 0.f};
    const int srcA = ((q4 & 1) * 2) * 16 + l16;
    const int srcB = srcA + 16;
    const bool hi = (q4 >= 2);
#pragma unroll
    for (int kc = 0; kc < 4; ++kc) {
        int ie = 2 * kc, io = 2 * kc + 1;
        unsigned a0e = __shfl(up[ie][0], srcA), a0o = __shfl(up[io][0], srcA);
        unsigned a1e = __shfl(up[ie][1], srcA), a1o = __shfl(up[io][1], srcA);
        unsigned b0e = __shfl(up[ie][0], srcB), b0o = __shfl(up[io][0], srcB);
        unsigned b1e = __shfl(up[ie][1], srcB), b1o = __shfl(up[io][1], srcB);
        union { uint4 u; short8 s; } cvt;
        cvt.u.x = hi ? a0o : a0e;
        cvt.u.y = hi ? a1o : a1e;
        cvt.u.z = hi ? b0o : b0e;
        cvt.u.w = hi ? b1o : b1e;
        short8 bv0 = *reinterpret_cast<const short8*>(&Vt[l16 * 136 + kc * 32 + q4 * 8]);
        short8 bv1 = *reinterpret_cast<const short8*>(&Vt[(16 + l16) * 136 + kc * 32 + q4 * 8]);
        o0 = __builtin_amdgcn_mfma_f32_16x16x32_bf16(cvt.s, bv0, o0, 0, 0, 0);
        o1 = __builtin_amdgcn_mfma_f32_16x16x32_bf16(cvt.s, bv1, o1, 0, 0, 0);
    }
    // store: row n' = tr*16 + q4*4 + r, cols d = l16 and 16+l16
#pragma unroll
    for (int r = 0; r < 4; ++r) {
        int nn = tr * 16 + q4 * 4 + r;
        if (nn < 98) {
            attn_out[obase + nn * 256 + l16] = f2bf(o0[r]);
            attn_out[obase + nn * 256 + 16 + l16] = f2bf(o1[r]);
        }
    }
}

// ---------------------------------------------------------------- proj GEMM
__global__ __launch_bounds__(256, 4)
void gemm_proj_kernel(const unsigned short* __restrict__ Abf,  // (M,256) bf16
                      const unsigned short* __restrict__ Wb,   // (256,256) bf16
                      const float* __restrict__ bias,
                      float* __restrict__ out) {
    __shared__ unsigned short As[128 * 64];
    __shared__ unsigned short Bs[128 * 64];
    const int tid = threadIdx.x;
    const int wave = tid >> 6, lane = tid & 63;
    const int q4 = lane >> 4, l16 = lane & 15;
    const int wr = wave >> 1, wc = wave & 1;

    // XCD-aware bijective swizzle (nwg = 2*1568 = 3136, 3136 % 8 == 0)
    const int nwg = gridDim.x * gridDim.y;
    const int bid = blockIdx.y * gridDim.x + blockIdx.x;
    const int swz = (bid & 7) * (nwg >> 3) + (bid >> 3);
    const int bx = swz % gridDim.x;
    const int by = swz / gridDim.x;

    const long m0 = (long)by * 128;
    const int n0 = bx * 128;

    const int srow = lane >> 3;
    const int scol = (lane & 7) << 3;

    f32x4 acc[4][4];
#pragma unroll
    for (int i = 0; i < 4; ++i)
#pragma unroll
        for (int j = 0; j < 4; ++j) acc[i][j] = (f32x4){0.f, 0.f, 0.f, 0.f};

    for (int ks = 0; ks < 256; ks += 64) {
#pragma unroll
        for (int i = 0; i < 4; ++i) {
            int c = wave * 4 + i;
            gload_lds16(Abf + (m0 + c * 8 + srow) * 256 + ks + scol, &As[c * 512]);
            gload_lds16(Wb + (long)(n0 + c * 8 + srow) * 256 + ks + scol, &Bs[c * 512]);
        }
        __syncthreads();
#pragma unroll
        for (int s = 0; s < 2; ++s) {
            short8 a[4], b[4];
#pragma unroll
            for (int i = 0; i < 4; ++i)
                a[i] = *reinterpret_cast<const short8*>(&As[(wr * 64 + i * 16 + l16) * 64 + s * 32 + q4 * 8]);
#pragma unroll
            for (int j = 0; j < 4; ++j)
                b[j] = *reinterpret_cast<const short8*>(&Bs[(wc * 64 + j * 16 + l16) * 64 + s * 32 + q4 * 8]);
#pragma unroll
            for (int i = 0; i < 4; ++i)
#pragma unroll
                for (int j = 0; j < 4; ++j)
                    acc[i][j] = __builtin_amdgcn_mfma_f32_16x16x32_bf16(a[i], b[j], acc[i][j], 0, 0, 0);
        }
        __syncthreads();
    }
#pragma unroll
    for (int i = 0; i < 4; ++i) {
#pragma unroll
        for (int r = 0; r < 4; ++r) {
            long row = m0 + wr * 64 + i * 16 + q4 * 4 + r;
#pragma unroll
            for (int j = 0; j < 4; ++j) {
                int col = n0 + wc * 64 + j * 16 + l16;
                out[row * 256 + col] = acc[i][j][r] + bias[col];
            }
        }
    }
}

// ---------------------------------------------------------------- launch
extern "C" void kernel_launch(void* const* d_in, const int* in_sizes, int n_in,
                              void* d_out, int out_size, void* d_ws, size_t ws_size,
                              hipStream_t stream) {
    (void)in_sizes; (void)n_in; (void)out_size; (void)ws_size;
    const float* x          = (const float*)d_in[0];
    const float* mask       = (const float*)d_in[1];
    const float* qkv_w      = (const float*)d_in[2];
    const float* qkv_b      = (const float*)d_in[3];
    const float* proj_w     = (const float*)d_in[4];
    const float* proj_b     = (const float*)d_in[5];
    const float* bias_table = (const float*)d_in[6];
    const int*   rel_index  = (const int*)d_in[7];
    float* out = (float*)d_out;

    const long QN = 51380224;   // 2048*8*98*32 (bf16 elems)
    const long VT = 58720256;   // 2048*8*32*112 (bf16 elems)
    unsigned short* qws  = (unsigned short*)d_ws;
    unsigned short* kws  = qws + QN;
    unsigned short* vtws = kws + QN;
    unsigned short* aow  = vtws + VT;                 // attn_out (M,256) bf16
    float* mask_padw = (float*)(aow + QN);            // 512*112*112 fp32
    float* bias_padw = mask_padw + 512 * 12544;       // 8*112*112 fp32
    unsigned short* wqkvb  = (unsigned short*)(bias_padw + 8 * 12544);  // 768*256
    unsigned short* wprojb = wqkvb + 768 * 256;                         // 256*256
    // Xb aliases aow: gemm_qkv's reads of Xb complete (stream order)
    // before attn_kernel writes attn_out into the same buffer.
    unsigned short* xb = aow;

    vt_zerofill_kernel<<<dim3((16384 * 32 * 7 + 255) / 256), dim3(256), 0, stream>>>(vtws);
    mask_pad_kernel<<<dim3((512 * 12544 + 255) / 256), dim3(256), 0, stream>>>(
        mask, mask_padw);
    bias_pad_kernel<<<dim3((8 * 12544 + 255) / 256), dim3(256), 0, stream>>>(
        bias_table, rel_index, bias_padw);
    cvt_bf16_kernel<<<dim3(2048), dim3(256), 0, stream>>>(x, xb, 51380224L / 8);
    cvt_bf16_kernel<<<dim3(96), dim3(256), 0, stream>>>(qkv_w, wqkvb, 196608L / 8);
    cvt_bf16_kernel<<<dim3(32), dim3(256), 0, stream>>>(proj_w, wprojb, 65536L / 8);
    gemm_qkv_kernel<<<dim3(6, 1568), dim3(256), 0, stream>>>(
        xb, wqkvb, qkv_b, qws, kws, vtws);
    attn_kernel<<<dim3(16384), dim3(448), 0, stream>>>(
        qws, kws, vtws, mask_padw, bias_padw, aow);
    gemm_proj_kernel<<<dim3(2, 1568), dim3(256), 0, stream>>>(
        aow, wprojb, proj_b, out);
}

// Round 3
// 825.073 us; speedup vs baseline: 1.4554x; 1.1176x over previous
//
#include <hip/hip_runtime.h>
#include <hip/hip_bf16.h>

typedef __attribute__((ext_vector_type(8))) short short8;
typedef __attribute__((ext_vector_type(4))) float f32x4;

__device__ __forceinline__ unsigned short f2bf(float f) {
    __hip_bfloat16 h = __float2bfloat16(f);
    union { __hip_bfloat16 h; unsigned short u; } c; c.h = h; return c.u;
}

typedef __attribute__((address_space(1))) const unsigned int gas_u32;
typedef __attribute__((address_space(3))) unsigned int las_u32;

// async global->LDS, 16B per lane; lds dst must be the wave-uniform base
__device__ __forceinline__ void gload_lds16(const unsigned short* g, unsigned short* l) {
    __builtin_amdgcn_global_load_lds((gas_u32*)g, (las_u32*)l, 16, 0, 0);
}

// ---------------------------------------------------------------- fp32 -> bf16
__global__ void cvt_bf16_kernel(const float* __restrict__ src,
                                unsigned short* __restrict__ dst, long n8) {
    long stride = (long)gridDim.x * 256;
    for (long t = (long)blockIdx.x * 256 + threadIdx.x; t < n8; t += stride) {
        long i = t * 8;
        float4 f0 = *reinterpret_cast<const float4*>(src + i);
        float4 f1 = *reinterpret_cast<const float4*>(src + i + 4);
        uint4 u;
        u.x = ((unsigned)f2bf(f0.y) << 16) | f2bf(f0.x);
        u.y = ((unsigned)f2bf(f0.w) << 16) | f2bf(f0.z);
        u.z = ((unsigned)f2bf(f1.y) << 16) | f2bf(f1.x);
        u.w = ((unsigned)f2bf(f1.w) << 16) | f2bf(f1.z);
        *reinterpret_cast<uint4*>(dst + i) = u;
    }
}

// ---------------------------------------------------------------- mask pad
// mask_pad (512,112,112): cols>=98 -> -1e30 (softmax kill), pad rows -> 0
__global__ void mask_pad_kernel(const float* __restrict__ mask,
                                float* __restrict__ mask_pad) {
    int idx = blockIdx.x * 256 + threadIdx.x;
    if (idx >= 512 * 12544) return;
    int w = idx / 12544, rem = idx - w * 12544;
    int n = rem / 112, m = rem - n * 112;
    float v;
    if (m >= 98) v = -1e30f;
    else if (n >= 98) v = 0.f;
    else v = mask[w * 9604 + n * 98 + m];
    mask_pad[idx] = v;
}

// ---------------------------------------------------------------- bias pad
// bias_pad (8,112,112): gathered rel-pos bias, pads -> 0
__global__ void bias_pad_kernel(const float* __restrict__ bias_table,
                                const int* __restrict__ rel_index,
                                float* __restrict__ bias_pad) {
    int idx = blockIdx.x * 256 + threadIdx.x;
    if (idx >= 8 * 12544) return;
    int h = idx / 12544, rem = idx - h * 12544;
    int n = rem / 112, m = rem - n * 112;
    float v = (n < 98 && m < 98) ? bias_table[rel_index[n * 98 + m] * 8 + h] : 0.f;
    bias_pad[idx] = v;
}

// ---------------------------------------------------------------- QKV GEMM
// m97 structure: 128x128 tile, BK=64, linear bf16 LDS, global_load_lds x16B.
// Epilogue: LDS repack -> fully coalesced 16B stores; Q,K,V all (bh,n,32).
__global__ __launch_bounds__(256, 4)
void gemm_qkv_kernel(const unsigned short* __restrict__ Xb,   // (M,256) bf16
                     const unsigned short* __restrict__ Wb,   // (768,256) bf16
                     const float* __restrict__ bias,
                     unsigned short* __restrict__ qws,
                     unsigned short* __restrict__ kws,
                     unsigned short* __restrict__ vws) {
    __shared__ unsigned short sh[17408];      // 34816 B; K-loop uses first 32KB
    unsigned short* As = sh;                  // 128*64
    unsigned short* Bs = sh + 8192;           // 128*64
    const int tid = threadIdx.x;
    const int wave = tid >> 6, lane = tid & 63;
    const int q4 = lane >> 4, l16 = lane & 15;
    const int wr = wave >> 1, wc = wave & 1;

    // XCD-aware bijective swizzle (nwg = 6*1568 = 9408, 9408 % 8 == 0)
    const int nwg = gridDim.x * gridDim.y;
    const int bid = blockIdx.y * gridDim.x + blockIdx.x;
    const int swz = (bid & 7) * (nwg >> 3) + (bid >> 3);
    const int bx = swz % gridDim.x;
    const int by = swz / gridDim.x;

    const long m0 = (long)by * 128;
    const int n0 = bx * 128;

    const int srow = lane >> 3;         // row within 8-row chunk
    const int scol = (lane & 7) << 3;   // col (elems) within 64

    f32x4 acc[4][4];
#pragma unroll
    for (int i = 0; i < 4; ++i)
#pragma unroll
        for (int j = 0; j < 4; ++j) acc[i][j] = (f32x4){0.f, 0.f, 0.f, 0.f};

    for (int ks = 0; ks < 256; ks += 64) {
#pragma unroll
        for (int i = 0; i < 4; ++i) {
            int c = wave * 4 + i;                       // chunk: 8 rows x 64 cols
            gload_lds16(Xb + (m0 + c * 8 + srow) * 256 + ks + scol, &As[c * 512]);
            gload_lds16(Wb + (long)(n0 + c * 8 + srow) * 256 + ks + scol, &Bs[c * 512]);
        }
        __syncthreads();   // compiler drains vmcnt+lgkmcnt here
#pragma unroll
        for (int s = 0; s < 2; ++s) {
            short8 a[4], b[4];
#pragma unroll
            for (int i = 0; i < 4; ++i)
                a[i] = *reinterpret_cast<const short8*>(&As[(wr * 64 + i * 16 + l16) * 64 + s * 32 + q4 * 8]);
#pragma unroll
            for (int j = 0; j < 4; ++j)
                b[j] = *reinterpret_cast<const short8*>(&Bs[(wc * 64 + j * 16 + l16) * 64 + s * 32 + q4 * 8]);
#pragma unroll
            for (int i = 0; i < 4; ++i)
#pragma unroll
                for (int j = 0; j < 4; ++j)
                    acc[i][j] = __builtin_amdgcn_mfma_f32_16x16x32_bf16(a[i], b[j], acc[i][j], 0, 0, 0);
        }
        __syncthreads();
    }

    // ---------------- epilogue: acc -> LDS (bf16, stride 136) -> coalesced out
    const float scale = (n0 < 256) ? 0.17677669529663687f : 1.0f;  // Q pre-scale
#pragma unroll
    for (int i = 0; i < 4; ++i) {
#pragma unroll
        for (int j = 0; j < 4; ++j) {
            int c = wc * 64 + j * 16 + l16;
            float bcol = bias[n0 + c];
#pragma unroll
            for (int r = 0; r < 4; ++r) {
                int row = wr * 64 + i * 16 + q4 * 4 + r;
                sh[row * 136 + c] = f2bf((acc[i][j][r] + bcol) * scale);
            }
        }
    }
    __syncthreads();

    const int whichb = n0 >> 8;        // 0=Q 1=K 2=V (block-uniform)
    unsigned short* dstm = (whichb == 0) ? qws : ((whichb == 1) ? kws : vws);
    const int cbase = n0 & 255;
#pragma unroll
    for (int it = 0; it < 8; ++it) {
        int id = it * 256 + tid;       // 0..2047
        int m = id >> 4;               // 0..127
        int ch = id & 15;              // 16B chunk (8 elems)
        uint4 u = *reinterpret_cast<const uint4*>(&sh[m * 136 + ch * 8]);
        long row = m0 + m;
        int b_ = (int)(row / 98);
        int n_ = (int)(row - (long)b_ * 98);
        int c = cbase + ch * 8;        // col within matrix, 0..255
        int h = c >> 5, d0 = c & 31;   // d0 in {0,8,16,24}
        *reinterpret_cast<uint4*>(dstm + (((long)(b_ * 8 + h) * 98 + n_) * 32 + d0)) = u;
    }
}

// ---------------------------------------------------------------- attention
// one block (448 thr = 7 waves) per (b,h); one 16-row S^T tile per wave.
// XCD swizzle keeps all 32 blocks sharing a mask window on one XCD's L2.
// V arrives (bh,98,32); transposed into LDS Vt[32][136] during staging.
__global__ __launch_bounds__(448, 7)
void attn_kernel(const unsigned short* __restrict__ q,
                 const unsigned short* __restrict__ k,
                 const unsigned short* __restrict__ v,       // (bh,98,32)
                 const float* __restrict__ mask_pad,         // (512,112,112)
                 const float* __restrict__ bias_pad,         // (8,112,112)
                 unsigned short* __restrict__ attn_out) {
    __shared__ unsigned short Qs[112 * 40];   // 8960 B
    __shared__ unsigned short Ks[112 * 40];   // 8960 B
    __shared__ unsigned short Vt[32 * 136];   // 8704 B (cols 0..127 used)

    const int tid = threadIdx.x;
    const int wave = tid >> 6, lane = tid & 63;
    const int q4 = lane >> 4, l16 = lane & 15;

    // blockIdx -> (b,h) with window locality per XCD (dispatch round-robins d&7)
    const int d0_ = blockIdx.x;
    const int xcd = d0_ & 7, jj = d0_ >> 3;
    const int w = xcd * 64 + (jj >> 5);       // 64 windows per XCD
    const int sub = jj & 31;                  // 4 b-reps x 8 heads share window w
    const int b = (sub >> 3) * 512 + w;
    const int h = sub & 7;
    const int bh = b * 8 + h;
    const long base = (long)bh * 98 * 32;

    {   // stage Q,K: one 16B chunk per thread (448 = 112 rows x 4 chunks)
        int n = tid >> 2, dg = (tid & 3) * 8;
        uint4 vq = make_uint4(0, 0, 0, 0), vk = make_uint4(0, 0, 0, 0);
        if (n < 98) {
            vq = *reinterpret_cast<const uint4*>(q + base + n * 32 + dg);
            vk = *reinterpret_cast<const uint4*>(k + base + n * 32 + dg);
        }
        *reinterpret_cast<uint4*>(&Qs[n * 40 + dg]) = vq;
        *reinterpret_cast<uint4*>(&Ks[n * 40 + dg]) = vk;
    }
    // zero Vt pad cols n in [98,128) for all d (disjoint from data writes)
    for (int i = tid; i < 32 * 30; i += 448) {
        int d = i / 30, nn = 98 + (i - d * 30);
        Vt[d * 136 + nn] = 0;
    }
    {   // stage V transposed: thread reads 8 d of one n, scatters to Vt[d][n]
        int n = tid >> 2, d0 = (tid & 3) * 8;
        if (n < 98) {
            union { uint4 u; unsigned short e[8]; } cvt;
            cvt.u = *reinterpret_cast<const uint4*>(v + base + n * 32 + d0);
#pragma unroll
            for (int kk = 0; kk < 8; ++kk) Vt[(d0 + kk) * 136 + n] = cvt.e[kk];
        }
    }
    __syncthreads();

    const float* mp = mask_pad + (long)w * 12544;
    const float* bp = bias_pad + (long)h * 12544;
    const long obase = (long)b * 98 * 256 + h * 32;

    const int tr = wave;                   // one tile per wave, 7 waves
    const int n = tr * 16 + l16;           // this lane's query row (<112)
    const float* mrow = mp + n * 112;
    const float* brow = bp + n * 112;
    short8 bq = *reinterpret_cast<const short8*>(&Qs[n * 40 + q4 * 8]);
    f32x4 pv[7];
#pragma unroll
    for (int i = 0; i < 7; ++i) {
        short8 ak = *reinterpret_cast<const short8*>(&Ks[(i * 16 + l16) * 40 + q4 * 8]);
        f32x4 d = (f32x4){0.f, 0.f, 0.f, 0.f};
        d = __builtin_amdgcn_mfma_f32_16x16x32_bf16(ak, bq, d, 0, 0, 0);
        // d[r] = S[n][m], m = i*16 + q4*4 + r; q pre-scaled
        int m0 = i * 16 + q4 * 4;
        float4 mk = *reinterpret_cast<const float4*>(mrow + m0);
        float4 bb = *reinterpret_cast<const float4*>(brow + m0);
        pv[i][0] = d[0] + mk.x + bb.x;
        pv[i][1] = d[1] + mk.y + bb.y;
        pv[i][2] = d[2] + mk.z + bb.z;
        pv[i][3] = d[3] + mk.w + bb.w;
    }
    // softmax over m (in-lane 28 values, then cross-quad lanes l16+{16,32,48})
    float mx = -1e30f;
#pragma unroll
    for (int i = 0; i < 7; ++i)
#pragma unroll
        for (int r = 0; r < 4; ++r) mx = fmaxf(mx, pv[i][r]);
    mx = fmaxf(mx, __shfl_xor(mx, 16));
    mx = fmaxf(mx, __shfl_xor(mx, 32));
    float sm = 0.f;
#pragma unroll
    for (int i = 0; i < 7; ++i)
#pragma unroll
        for (int r = 0; r < 4; ++r) {
            float e = __expf(pv[i][r] - mx);
            pv[i][r] = e;
            sm += e;
        }
    sm += __shfl_xor(sm, 16);
    sm += __shfl_xor(sm, 32);
    float rinv = 1.f / sm;
    // pack normalized P as bf16 pairs
    unsigned up[8][2];
#pragma unroll
    for (int i = 0; i < 7; ++i) {
        up[i][0] = ((unsigned)f2bf(pv[i][1] * rinv) << 16) | f2bf(pv[i][0] * rinv);
        up[i][1] = ((unsigned)f2bf(pv[i][3] * rinv) << 16) | f2bf(pv[i][2] * rinv);
    }
    up[7][0] = 0; up[7][1] = 0;
    // PV: shuffle P into A-operand layout, accumulate over kc
    f32x4 o0 = (f32x4){0.f, 0.f, 0.f, 0.f};
    f32x4 o1 = (f32x4){0.f, 0.f, 0.f, 0.f};
    const int srcA = ((q4 & 1) * 2) * 16 + l16;
    const int srcB = srcA + 16;
    const bool hi = (q4 >= 2);
#pragma unroll
    for (int kc = 0; kc < 4; ++kc) {
        int ie = 2 * kc, io = 2 * kc + 1;
        unsigned a0e = __shfl(up[ie][0], srcA), a0o = __shfl(up[io][0], srcA);
        unsigned a1e = __shfl(up[ie][1], srcA), a1o = __shfl(up[io][1], srcA);
        unsigned b0e = __shfl(up[ie][0], srcB), b0o = __shfl(up[io][0], srcB);
        unsigned b1e = __shfl(up[ie][1], srcB), b1o = __shfl(up[io][1], srcB);
        union { uint4 u; short8 s; } cvt;
        cvt.u.x = hi ? a0o : a0e;
        cvt.u.y = hi ? a1o : a1e;
        cvt.u.z = hi ? b0o : b0e;
        cvt.u.w = hi ? b1o : b1e;
        short8 bv0 = *reinterpret_cast<const short8*>(&Vt[l16 * 136 + kc * 32 + q4 * 8]);
        short8 bv1 = *reinterpret_cast<const short8*>(&Vt[(16 + l16) * 136 + kc * 32 + q4 * 8]);
        o0 = __builtin_amdgcn_mfma_f32_16x16x32_bf16(cvt.s, bv0, o0, 0, 0, 0);
        o1 = __builtin_amdgcn_mfma_f32_16x16x32_bf16(cvt.s, bv1, o1, 0, 0, 0);
    }
    // store: row n' = tr*16 + q4*4 + r, cols d = l16 and 16+l16
#pragma unroll
    for (int r = 0; r < 4; ++r) {
        int nn = tr * 16 + q4 * 4 + r;
        if (nn < 98) {
            attn_out[obase + nn * 256 + l16] = f2bf(o0[r]);
            attn_out[obase + nn * 256 + 16 + l16] = f2bf(o1[r]);
        }
    }
}

// ---------------------------------------------------------------- proj GEMM
__global__ __launch_bounds__(256, 4)
void gemm_proj_kernel(const unsigned short* __restrict__ Abf,  // (M,256) bf16
                      const unsigned short* __restrict__ Wb,   // (256,256) bf16
                      const float* __restrict__ bias,
                      float* __restrict__ out) {
    __shared__ unsigned short As[128 * 64];
    __shared__ unsigned short Bs[128 * 64];
    const int tid = threadIdx.x;
    const int wave = tid >> 6, lane = tid & 63;
    const int q4 = lane >> 4, l16 = lane & 15;
    const int wr = wave >> 1, wc = wave & 1;

    // XCD-aware bijective swizzle (nwg = 2*1568 = 3136, 3136 % 8 == 0)
    const int nwg = gridDim.x * gridDim.y;
    const int bid = blockIdx.y * gridDim.x + blockIdx.x;
    const int swz = (bid & 7) * (nwg >> 3) + (bid >> 3);
    const int bx = swz % gridDim.x;
    const int by = swz / gridDim.x;

    const long m0 = (long)by * 128;
    const int n0 = bx * 128;

    const int srow = lane >> 3;
    const int scol = (lane & 7) << 3;

    f32x4 acc[4][4];
#pragma unroll
    for (int i = 0; i < 4; ++i)
#pragma unroll
        for (int j = 0; j < 4; ++j) acc[i][j] = (f32x4){0.f, 0.f, 0.f, 0.f};

    for (int ks = 0; ks < 256; ks += 64) {
#pragma unroll
        for (int i = 0; i < 4; ++i) {
            int c = wave * 4 + i;
            gload_lds16(Abf + (m0 + c * 8 + srow) * 256 + ks + scol, &As[c * 512]);
            gload_lds16(Wb + (long)(n0 + c * 8 + srow) * 256 + ks + scol, &Bs[c * 512]);
        }
        __syncthreads();
#pragma unroll
        for (int s = 0; s < 2; ++s) {
            short8 a[4], b[4];
#pragma unroll
            for (int i = 0; i < 4; ++i)
                a[i] = *reinterpret_cast<const short8*>(&As[(wr * 64 + i * 16 + l16) * 64 + s * 32 + q4 * 8]);
#pragma unroll
            for (int j = 0; j < 4; ++j)
                b[j] = *reinterpret_cast<const short8*>(&Bs[(wc * 64 + j * 16 + l16) * 64 + s * 32 + q4 * 8]);
#pragma unroll
            for (int i = 0; i < 4; ++i)
#pragma unroll
                for (int j = 0; j < 4; ++j)
                    acc[i][j] = __builtin_amdgcn_mfma_f32_16x16x32_bf16(a[i], b[j], acc[i][j], 0, 0, 0);
        }
        __syncthreads();
    }
#pragma unroll
    for (int i = 0; i < 4; ++i) {
#pragma unroll
        for (int r = 0; r < 4; ++r) {
            long row = m0 + wr * 64 + i * 16 + q4 * 4 + r;
#pragma unroll
            for (int j = 0; j < 4; ++j) {
                int col = n0 + wc * 64 + j * 16 + l16;
                out[row * 256 + col] = acc[i][j][r] + bias[col];
            }
        }
    }
}

// ---------------------------------------------------------------- launch
extern "C" void kernel_launch(void* const* d_in, const int* in_sizes, int n_in,
                              void* d_out, int out_size, void* d_ws, size_t ws_size,
                              hipStream_t stream) {
    (void)in_sizes; (void)n_in; (void)out_size; (void)ws_size;
    const float* x          = (const float*)d_in[0];
    const float* mask       = (const float*)d_in[1];
    const float* qkv_w      = (const float*)d_in[2];
    const float* qkv_b      = (const float*)d_in[3];
    const float* proj_w     = (const float*)d_in[4];
    const float* proj_b     = (const float*)d_in[5];
    const float* bias_table = (const float*)d_in[6];
    const int*   rel_index  = (const int*)d_in[7];
    float* out = (float*)d_out;

    const long QN = 51380224;   // 2048*8*98*32 (bf16 elems)
    unsigned short* qws  = (unsigned short*)d_ws;
    unsigned short* kws  = qws + QN;
    unsigned short* vws  = kws + QN;
    unsigned short* aow  = vws + QN;                  // attn_out (M,256) bf16
    float* mask_padw = (float*)(aow + QN);            // 512*112*112 fp32
    float* bias_padw = mask_padw + 512 * 12544;       // 8*112*112 fp32
    unsigned short* wqkvb  = (unsigned short*)(bias_padw + 8 * 12544);  // 768*256
    unsigned short* wprojb = wqkvb + 768 * 256;                         // 256*256
    // Xb aliases aow: gemm_qkv's reads of Xb complete (stream order)
    // before attn_kernel writes attn_out into the same buffer.
    unsigned short* xb = aow;

    mask_pad_kernel<<<dim3((512 * 12544 + 255) / 256), dim3(256), 0, stream>>>(
        mask, mask_padw);
    bias_pad_kernel<<<dim3((8 * 12544 + 255) / 256), dim3(256), 0, stream>>>(
        bias_table, rel_index, bias_padw);
    cvt_bf16_kernel<<<dim3(2048), dim3(256), 0, stream>>>(x, xb, 51380224L / 8);
    cvt_bf16_kernel<<<dim3(96), dim3(256), 0, stream>>>(qkv_w, wqkvb, 196608L / 8);
    cvt_bf16_kernel<<<dim3(32), dim3(256), 0, stream>>>(proj_w, wprojb, 65536L / 8);
    gemm_qkv_kernel<<<dim3(6, 1568), dim3(256), 0, stream>>>(
        xb, wqkvb, qkv_b, qws, kws, vws);
    attn_kernel<<<dim3(16384), dim3(448), 0, stream>>>(
        qws, kws, vws, mask_padw, bias_padw, aow);
    gemm_proj_kernel<<<dim3(2, 1568), dim3(256), 0, stream>>>(
        aow, wprojb, proj_b, out);
}